// Round 17
// baseline (1645.176 us; speedup 1.0000x reference)
//
#include <hip/hip_runtime.h>
#include <hip/hip_bf16.h>
#include <math.h>

#define T_LEN 1024
#define NB    8
#define CCH   512
#define FCH   2048
#define NH    8
#define HD    64
#define NL    6
#define TP    1032   // padded time rows per batch: [1 pre][1024][7 post]
#define LOG2E 1.44269504f

typedef short bf16x8 __attribute__((ext_vector_type(8)));
typedef float f32x4  __attribute__((ext_vector_type(4)));

typedef __attribute__((address_space(1))) const void gvoid_t;
typedef __attribute__((address_space(3))) void lvoid_t;

static __device__ __forceinline__ float b2f(short s) {
    union { unsigned u; float f; } cv; cv.u = ((unsigned)(unsigned short)s) << 16; return cv.f;
}
static __device__ __forceinline__ short f2b(float f) {
    union { __hip_bfloat16 h; short s; } cv; cv.h = __float2bfloat16(f); return cv.s;
}
// raw v_exp_f32: D = 2^S0
static __device__ __forceinline__ float exp2_hw(float x) {
    float r; asm("v_exp_f32 %0, %1" : "=v"(r) : "v"(x)); return r;
}

// ---------------------------------------------------------------------------
// conv1 256x256 counted-vmcnt pipelined GEMM (KS=3, relu, padded bf16 out).
// Proven R16: 8 waves, BK=64, LDS 128KB dbuf, vmcnt(4), no sched pins.
// ---------------------------------------------------------------------------
__global__ __launch_bounds__(512)
void conv1_256(const short* __restrict__ Xb, const short* __restrict__ Wb,
               const float* __restrict__ Bias, short* __restrict__ outB)
{
    __shared__ short abuf[2][256 * 64];
    __shared__ short bbuf[2][256 * 64];

    const int tid  = threadIdx.x;
    const int wave = tid >> 6, lane = tid & 63;
    const int l15  = lane & 15, l16 = lane >> 4;
    const int wm   = wave >> 2, wn = wave & 3;
    const int srow = lane >> 3;
    const int xsw  = ((lane & 7) ^ (srow & 7)) << 3;

    const int t0 = blockIdx.x * 256;
    const int o0 = blockIdx.y * 256;
    const int b  = blockIdx.z;

    constexpr int NK = 24;               // 3 taps x 8 chunks of 64
    const size_t arow0 = (size_t)b * TP + t0;

    auto stageA = [&](int kcg, short* dst) {
        const int tap = kcg >> 3;
        const int c0  = (kcg & 7) << 6;
        const short* base = Xb + (arow0 + tap) * CCH + c0 + xsw;
        #pragma unroll
        for (int i = 0; i < 4; ++i) {
            const int j = wave + 8 * i;
            __builtin_amdgcn_global_load_lds((gvoid_t*)(base + (size_t)(j * 8 + srow) * CCH),
                                             (lvoid_t*)(dst + j * 512), 16, 0, 0);
        }
    };
    auto stageB = [&](int kcg, short* dst) {
        const int tap = kcg >> 3;
        const int c0  = (kcg & 7) << 6;
        const short* base = Wb + ((size_t)tap * FCH + o0) * CCH + c0 + xsw;
        #pragma unroll
        for (int i = 0; i < 4; ++i) {
            const int j = wave + 8 * i;
            __builtin_amdgcn_global_load_lds((gvoid_t*)(base + (size_t)(j * 8 + srow) * CCH),
                                             (lvoid_t*)(dst + j * 512), 16, 0, 0);
        }
    };

    f32x4 acc[8][4];
    #pragma unroll
    for (int i = 0; i < 8; ++i)
        #pragma unroll
        for (int j = 0; j < 4; ++j) acc[i][j] = (f32x4){0.f, 0.f, 0.f, 0.f};

    stageA(0, abuf[0]);
    stageB(0, bbuf[0]);

    for (int kc = 0; kc < NK; ++kc) {
        const int cur = kc & 1, nxt = cur ^ 1;
        const int kn  = (kc + 1 < NK) ? (kc + 1) : kc;

        __builtin_amdgcn_s_barrier();
        stageA(kn, abuf[nxt]);
        asm volatile("s_waitcnt vmcnt(4)" ::: "memory");
        __builtin_amdgcn_s_barrier();

        #pragma unroll
        for (int ks = 0; ks < 2; ++ks) {
            if (ks == 1) stageB(kn, bbuf[nxt]);
            bf16x8 af[8], bfr[4];
            #pragma unroll
            for (int fm = 0; fm < 8; ++fm) {
                const int ra = wm * 128 + fm * 16 + l15;
                af[fm] = *(const bf16x8*)&abuf[cur][ra * 64 + (((ks * 4 + l16) ^ (ra & 7)) << 3)];
            }
            #pragma unroll
            for (int fn = 0; fn < 4; ++fn) {
                const int rb = wn * 64 + fn * 16 + l15;
                bfr[fn] = *(const bf16x8*)&bbuf[cur][rb * 64 + (((ks * 4 + l16) ^ (rb & 7)) << 3)];
            }
            __builtin_amdgcn_s_setprio(1);
            #pragma unroll
            for (int fm = 0; fm < 8; ++fm)
                #pragma unroll
                for (int fn = 0; fn < 4; ++fn)
                    acc[fm][fn] = __builtin_amdgcn_mfma_f32_16x16x32_bf16(
                        af[fm], bfr[fn], acc[fm][fn], 0, 0, 0);
            __builtin_amdgcn_s_setprio(0);
        }
    }

    float bias_v[4];
    #pragma unroll
    for (int fn = 0; fn < 4; ++fn)
        bias_v[fn] = Bias[o0 + wn * 64 + fn * 16 + l15];

    #pragma unroll
    for (int fm = 0; fm < 8; ++fm) {
        #pragma unroll
        for (int r = 0; r < 4; ++r) {
            const int t_loc = wm * 128 + fm * 16 + l16 * 4 + r;
            const size_t orow = (size_t)b * TP + t0 + t_loc + 1;
            #pragma unroll
            for (int fn = 0; fn < 4; ++fn) {
                const int o = o0 + wn * 64 + fn * 16 + l15;
                outB[orow * FCH + o] = f2b(fmaxf(acc[fm][fn][r] + bias_v[fn], 0.f));
            }
        }
    }

    if (t0 == 0)
        for (int cc = tid; cc < 256; cc += 512)
            outB[((size_t)b * TP) * FCH + o0 + cc] = 0;
    if (t0 == T_LEN - 256)
        for (int idx = tid; idx < 7 * 256; idx += 512) {
            const int rr = idx >> 8, cc = idx & 255;
            outB[((size_t)b * TP + 1025 + rr) * FCH + o0 + cc] = 0;
        }
}

// ---------------------------------------------------------------------------
// 128x128 counted-vmcnt pipelined GEMM / conv1d.  4 waves, BK=64, LDS 64KB
// double-buffered (2 blocks/CU), vmcnt(4), no sched pins, setprio on MFMA.
// Taps flattened into the K-chunk index (tap-shifted padded A rows).
// OMODE: 0 bf16 flat [rows][O]; 2 split-K=2 (split0 +bias -> outB1, split1
//        -> outB2).  VTOUT: o0>=1024 blocks write transposed VT (LDS
//        re-stage after vmcnt(0) drain) and skip the flat store.
// ---------------------------------------------------------------------------
template<int KSZ, bool RELU, int OMODE, bool VTOUT>
__global__ __launch_bounds__(256)
void mfma_gemm(const short* __restrict__ Xb, const short* __restrict__ Wb,
               const float* __restrict__ Bias,
               short* __restrict__ outB1, short* __restrict__ outB2,
               short* __restrict__ VTout,
               int Cin, int O, int ksplit)
{
    __shared__ short abuf[2][128 * 64];
    __shared__ short bbuf[2][128 * 64];

    const int tid  = threadIdx.x;
    const int wave = tid >> 6, lane = tid & 63;
    const int l15  = lane & 15, l16 = lane >> 4;
    const int wm   = wave >> 1, wn = wave & 1;
    const int srow = lane >> 3;
    const int xsw  = ((lane & 7) ^ (srow & 7)) << 3;

    const int t0 = blockIdx.x * 128;
    const int o0 = blockIdx.y * 128;
    const int zz = blockIdx.z;
    const int b     = zz / ksplit;
    const int split = zz - b * ksplit;

    const int cpt = Cin >> 6;                  // chunks per tap
    const int NK  = (cpt * KSZ) / ksplit;      // chunks this split
    const int kbase = split * NK;

    const size_t xrowbase = (KSZ == 3) ? ((size_t)b * TP + t0) : (size_t)t0;

    auto stageA = [&](int kcg, short* dst) {
        const int tap = (KSZ == 3) ? (kcg / cpt) : 0;
        const int c0  = (kcg - tap * cpt) << 6;
        const short* base = Xb + (xrowbase + tap) * Cin + c0 + xsw;
        #pragma unroll
        for (int i = 0; i < 4; ++i) {
            const int j = wave + 4 * i;
            __builtin_amdgcn_global_load_lds((gvoid_t*)(base + (size_t)(j * 8 + srow) * Cin),
                                             (lvoid_t*)(dst + j * 512), 16, 0, 0);
        }
    };
    auto stageB = [&](int kcg, short* dst) {
        const int tap = (KSZ == 3) ? (kcg / cpt) : 0;
        const int c0  = (kcg - tap * cpt) << 6;
        const short* base = Wb + ((size_t)tap * O + o0) * Cin + c0 + xsw;
        #pragma unroll
        for (int i = 0; i < 4; ++i) {
            const int j = wave + 4 * i;
            __builtin_amdgcn_global_load_lds((gvoid_t*)(base + (size_t)(j * 8 + srow) * Cin),
                                             (lvoid_t*)(dst + j * 512), 16, 0, 0);
        }
    };

    f32x4 acc[4][4];
    #pragma unroll
    for (int i = 0; i < 4; ++i)
        #pragma unroll
        for (int j = 0; j < 4; ++j) acc[i][j] = (f32x4){0.f, 0.f, 0.f, 0.f};

    stageA(kbase, abuf[0]);
    stageB(kbase, bbuf[0]);

    for (int kc = 0; kc < NK; ++kc) {
        const int cur = kc & 1, nxt = cur ^ 1;
        const int kn  = kbase + ((kc + 1 < NK) ? (kc + 1) : kc);

        __builtin_amdgcn_s_barrier();          // prev tile's reads of buf[nxt] done
        stageA(kn, abuf[nxt]);
        asm volatile("s_waitcnt vmcnt(4)" ::: "memory");   // tile kc (A+B) landed
        __builtin_amdgcn_s_barrier();          // all waves see tile kc

        #pragma unroll
        for (int ks = 0; ks < 2; ++ks) {
            if (ks == 1) stageB(kn, bbuf[nxt]);
            bf16x8 af[4], bfr[4];
            #pragma unroll
            for (int f = 0; f < 4; ++f) {
                const int ra = wm * 64 + f * 16 + l15;
                af[f] = *(const bf16x8*)&abuf[cur][ra * 64 + (((ks * 4 + l16) ^ (ra & 7)) << 3)];
                const int rb = wn * 64 + f * 16 + l15;
                bfr[f] = *(const bf16x8*)&bbuf[cur][rb * 64 + (((ks * 4 + l16) ^ (rb & 7)) << 3)];
            }
            __builtin_amdgcn_s_setprio(1);
            #pragma unroll
            for (int fm = 0; fm < 4; ++fm)
                #pragma unroll
                for (int fn = 0; fn < 4; ++fn)
                    acc[fm][fn] = __builtin_amdgcn_mfma_f32_16x16x32_bf16(
                        af[fm], bfr[fn], acc[fm][fn], 0, 0, 0);
            __builtin_amdgcn_s_setprio(0);
        }
    }

    float bias_v[4];
    #pragma unroll
    for (int fn = 0; fn < 4; ++fn)
        bias_v[fn] = (OMODE != 2 || split == 0) ? Bias[o0 + wn * 64 + fn * 16 + l15] : 0.f;

    const bool vtblk = VTOUT && (o0 >= 1024);

    if (vtblk) {
        // drain final prefetch (its LDS writes target the buffers we reuse)
        asm volatile("s_waitcnt vmcnt(0)" ::: "memory");
        __syncthreads();
        short* tb = &abuf[0][0];   // 128(o_local) x 128(t_loc), chunk-XOR swizzled
        #pragma unroll
        for (int fm = 0; fm < 4; ++fm)
            #pragma unroll
            for (int r = 0; r < 4; ++r) {
                const int t_loc = wm * 64 + fm * 16 + l16 * 4 + r;
                #pragma unroll
                for (int fn = 0; fn < 4; ++fn) {
                    const int ol = wn * 64 + fn * 16 + l15;
                    tb[ol * 128 + (((t_loc >> 3) ^ (ol & 7)) << 3) + (t_loc & 7)]
                        = f2b(acc[fm][fn][r] + bias_v[fn]);
                }
            }
        __syncthreads();
        const int bq  = t0 >> 10, tin = t0 & 1023;
        const int vcb = o0 - 1024;
        #pragma unroll
        for (int p = 0; p < 8; ++p) {
            const int drow  = (tid >> 4) + p * 16;
            const int chunk = tid & 15;
            bf16x8 v = *(const bf16x8*)&tb[drow * 128 + ((chunk ^ (drow & 7)) << 3)];
            const int vc = vcb + drow;
            *(bf16x8*)&VTout[((size_t)(bq * NH + (vc >> 6)) * HD + (vc & 63)) * T_LEN
                             + tin + chunk * 8] = v;
        }
    } else {
        #pragma unroll
        for (int fm = 0; fm < 4; ++fm) {
            #pragma unroll
            for (int r = 0; r < 4; ++r) {
                const int t_loc = wm * 64 + fm * 16 + l16 * 4 + r;
                const size_t orow = (KSZ == 3) ? ((size_t)b * T_LEN + t0 + t_loc)
                                               : (size_t)(t0 + t_loc);
                #pragma unroll
                for (int fn = 0; fn < 4; ++fn) {
                    const int o = o0 + wn * 64 + fn * 16 + l15;
                    float v = acc[fm][fn][r] + bias_v[fn];
                    if (RELU) v = fmaxf(v, 0.f);
                    const size_t idx = orow * (size_t)O + o;
                    if (OMODE == 2) {
                        if (split == 0) outB1[idx] = f2b(v);
                        else            outB2[idx] = f2b(v);
                    } else {
                        outB1[idx] = f2b(v);
                    }
                }
            }
        }
    }
}

// ---------------------------------------------------------------------------
// MFMA flash attention — proven 86.5 us form (unchanged from R16).
// ---------------------------------------------------------------------------
__global__ __launch_bounds__(512)
void attn_mfma(const short* __restrict__ QKV, const short* __restrict__ VT,
               const float* __restrict__ erk, const float* __restrict__ erv,
               short* __restrict__ Yat)
{
    const int n = blockIdx.x;
    const int c = n & 7, g = n >> 3;
    const int bh = c * 8 + (g & 7);
    const int qt = g >> 3;
    const int b = bh >> 3, h = bh & 7;
    const int tq0 = qt * 128;
    const int hq = h * HD;
    const size_t bt0 = (size_t)b * T_LEN;

    __shared__ short ql[128 * 64];   // prologue: Q; main loop: pl buffer (odd tiles)
    __shared__ short pl0[128 * 64];  // pl buffer (even tiles)
    __shared__ short kl[2][64 * 64];
    __shared__ short vl[2][64 * 64];
    __shared__ float qerkl[128][12];
    __shared__ float ervl[9][64];

    const int tid  = threadIdx.x;
    const int wave = tid >> 6, lane = tid & 63;
    const int l15  = lane & 15, l16 = lane >> 4;
    const int srow = lane >> 3;
    const int xsw  = ((lane & 7) ^ (srow & 7)) << 3;

    const short* vbase = VT + (size_t)bh * HD * T_LEN;

    for (int j = wave; j < 16; j += 8) {
        const short* src = QKV + (bt0 + tq0 + j * 8 + srow) * 1536 + hq + xsw;
        __builtin_amdgcn_global_load_lds((gvoid_t*)src, (lvoid_t*)&ql[j * 512], 16, 0, 0);
    }
    {
        const short* ksrc = QKV + (bt0 + wave * 8 + srow) * 1536 + 512 + hq + xsw;
        __builtin_amdgcn_global_load_lds((gvoid_t*)ksrc, (lvoid_t*)&kl[0][wave * 512], 16, 0, 0);
        const short* vsrc = vbase + (size_t)(wave * 8 + srow) * T_LEN + xsw;
        __builtin_amdgcn_global_load_lds((gvoid_t*)vsrc, (lvoid_t*)&vl[0][wave * 512], 16, 0, 0);
    }
    for (int i = tid; i < 9 * 64; i += 512) ervl[i >> 6][i & 63] = erv[i];
    __syncthreads();   // Q/K0/V0 landed; ervl visible

    // Q A-fragments -> registers
    bf16x8 af[2];
    #pragma unroll
    for (int ks = 0; ks < 2; ++ks) {
        const int r0 = wave * 16 + l15;
        af[ks] = *(const bf16x8*)&ql[r0 * 64 + (((ks * 4 + l16) ^ (r0 & 7)) << 3)];
    }

    // qerk[r][o] = q[r].erk[o]  (q carries log2e)
    for (int idx = tid; idx < 128 * 9; idx += 512) {
        const int r = idx / 9, o = idx - r * 9;
        float s = 0.f;
        for (int d = 0; d < 64; ++d) {
            float qv = b2f(ql[r * 64 + (((d >> 3) ^ (r & 7)) << 3) + (d & 7)]);
            s += qv * erk[o * 64 + d];
        }
        qerkl[r][o] = s;
    }

    float lsum[4] = {0.f, 0.f, 0.f, 0.f};
    f32x4 acco[4];
    #pragma unroll
    for (int fn = 0; fn < 4; ++fn) acco[fn] = (f32x4){0.f, 0.f, 0.f, 0.f};
    bf16x8 vf[2][4];   // V fragments of the previous tile

    const int ra = wave * 16 + l15;

    for (int it = 0; it < 16; ++it) {
        const int cur = it & 1;
        const int s0  = it * 64;
        __syncthreads();   // stage(it) landed; prev-iter ds_reads drained

        if (it < 15) {     // prefetch tile it+1
            const short* ksrc = QKV + (bt0 + s0 + 64 + wave * 8 + srow) * 1536 + 512 + hq + xsw;
            __builtin_amdgcn_global_load_lds((gvoid_t*)ksrc, (lvoid_t*)&kl[cur ^ 1][wave * 512], 16, 0, 0);
            const short* vsrc = vbase + (size_t)(wave * 8 + srow) * T_LEN + s0 + 64 + xsw;
            __builtin_amdgcn_global_load_lds((gvoid_t*)vsrc, (lvoid_t*)&vl[cur ^ 1][wave * 512], 16, 0, 0);
        }

        // QK^T(it)
        f32x4 sc[4];
        #pragma unroll
        for (int fn = 0; fn < 4; ++fn) sc[fn] = (f32x4){0.f, 0.f, 0.f, 0.f};
        __builtin_amdgcn_s_setprio(1);
        #pragma unroll
        for (int ks = 0; ks < 2; ++ks)
            #pragma unroll
            for (int fn = 0; fn < 4; ++fn) {
                const int rb = fn * 16 + l15;
                bf16x8 bf = *(const bf16x8*)&kl[cur][rb * 64 + (((ks * 4 + l16) ^ (rb & 7)) << 3)];
                sc[fn] = __builtin_amdgcn_mfma_f32_16x16x32_bf16(af[ks], bf, sc[fn], 0, 0, 0);
            }
        __builtin_amdgcn_s_setprio(0);

        // PV(it-1) + rel-v(it-1): prev pl buffer + vf registers
        if (it > 0) {
            short* plp = cur ? pl0 : ql;
            __builtin_amdgcn_s_setprio(1);
            #pragma unroll
            for (int ks = 0; ks < 2; ++ks) {
                bf16x8 paf = *(const bf16x8*)&plp[ra * 64 + (((ks * 4 + l16) ^ (ra & 7)) << 3)];
                #pragma unroll
                for (int fn = 0; fn < 4; ++fn)
                    acco[fn] = __builtin_amdgcn_mfma_f32_16x16x32_bf16(paf, vf[ks][fn], acco[fn], 0, 0, 0);
            }
            __builtin_amdgcn_s_setprio(0);
            const int s0p = s0 - 64;
            if ((s0p >= tq0 - 64) && (s0p <= tq0 + 128)) {
                #pragma unroll
                for (int r = 0; r < 4; ++r) {
                    const int q_loc = wave * 16 + l16 * 4 + r;
                    const int qg = tq0 + q_loc;
                    #pragma unroll
                    for (int o = 0; o < 9; ++o) {
                        const int jj = qg + o - 4 - s0p;
                        if (jj >= 0 && jj < 64) {
                            const float p = b2f(plp[q_loc * 64
                                + (((jj >> 3) ^ (q_loc & 7)) << 3) + (jj & 7)]);
                            #pragma unroll
                            for (int fn = 0; fn < 4; ++fn)
                                acco[fn][r] += p * ervl[o][fn * 16 + l15];
                        }
                    }
                }
            }
        }

        // hoist V(it) fragments -> registers (consumed next iter / epilogue)
        #pragma unroll
        for (int ks = 0; ks < 2; ++ks)
            #pragma unroll
            for (int fn = 0; fn < 4; ++fn) {
                const int rb = fn * 16 + l15;
                vf[ks][fn] = *(const bf16x8*)&vl[cur][rb * 64 + (((ks * 4 + l16) ^ (rb & 7)) << 3)];
            }

        // rel-k band + exp2 softmax
        if ((s0 >= tq0 - 64) && (s0 <= tq0 + 128)) {
            #pragma unroll
            for (int fn = 0; fn < 4; ++fn)
                #pragma unroll
                for (int r = 0; r < 4; ++r) {
                    const int q_loc = wave * 16 + l16 * 4 + r;
                    const int off = (s0 + fn * 16 + l15) - (tq0 + q_loc);
                    if (off >= -4 && off <= 4)
                        sc[fn][r] += qerkl[q_loc][off + 4];
                }
        }
        #pragma unroll
        for (int fn = 0; fn < 4; ++fn)
            #pragma unroll
            for (int r = 0; r < 4; ++r) {
                const float p = exp2_hw(sc[fn][r]);
                sc[fn][r] = p;
                lsum[r] += p;
            }

        // write P(it) into this tile's pl buffer (wave-private rows)
        {
            short* plw = cur ? ql : pl0;
            #pragma unroll
            for (int fn = 0; fn < 4; ++fn)
                #pragma unroll
                for (int r = 0; r < 4; ++r) {
                    const int q_loc = wave * 16 + l16 * 4 + r;
                    const int s_loc = fn * 16 + l15;
                    plw[q_loc * 64 + (((s_loc >> 3) ^ (q_loc & 7)) << 3) + (s_loc & 7)]
                        = f2b(sc[fn][r]);
                }
        }
    }

    // epilogue: PV(15) + rel-v(15)
    __syncthreads();
    {
        short* plp = ql;
        #pragma unroll
        for (int ks = 0; ks < 2; ++ks) {
            bf16x8 paf = *(const bf16x8*)&plp[ra * 64 + (((ks * 4 + l16) ^ (ra & 7)) << 3)];
            #pragma unroll
            for (int fn = 0; fn < 4; ++fn)
                acco[fn] = __builtin_amdgcn_mfma_f32_16x16x32_bf16(paf, vf[ks][fn], acco[fn], 0, 0, 0);
        }
        const int s0p = 960;
        if ((s0p >= tq0 - 64) && (s0p <= tq0 + 128)) {
            #pragma unroll
            for (int r = 0; r < 4; ++r) {
                const int q_loc = wave * 16 + l16 * 4 + r;
                const int qg = tq0 + q_loc;
                #pragma unroll
                for (int o = 0; o < 9; ++o) {
                    const int jj = qg + o - 4 - s0p;
                    if (jj >= 0 && jj < 64) {
                        const float p = b2f(plp[q_loc * 64
                            + (((jj >> 3) ^ (q_loc & 7)) << 3) + (jj & 7)]);
                        #pragma unroll
                        for (int fn = 0; fn < 4; ++fn)
                            acco[fn][r] += p * ervl[o][fn * 16 + l15];
                    }
                }
            }
        }
    }

    #pragma unroll
    for (int r = 0; r < 4; ++r) {
        float l = lsum[r];
        l += __shfl_xor(l, 1);
        l += __shfl_xor(l, 2);
        l += __shfl_xor(l, 4);
        l += __shfl_xor(l, 8);
        const float inv = 1.f / l;
        const int q_loc = wave * 16 + l16 * 4 + r;
        const size_t row = (bt0 + tq0 + q_loc) * CCH + hq;
        #pragma unroll
        for (int fn = 0; fn < 4; ++fn)
            Yat[row + fn * 16 + l15] = f2b(acco[fn][r] * inv);
    }
}

// ---------------------------------------------------------------------------
// Residual + LayerNorm, full-bf16 stream (unchanged).
// ---------------------------------------------------------------------------
__global__ __launch_bounds__(256)
void ln_kernel(const short* __restrict__ X, const short* __restrict__ Y1b,
               const short* __restrict__ Y2b, const float* __restrict__ g,
               const float* __restrict__ bb, short* __restrict__ outB,
               int xpad, int opad)
{
    const int wave = threadIdx.x >> 6, lane = threadIdx.x & 63;
    const int row  = blockIdx.x * 4 + wave;
    const int c = lane * 8;
    const size_t frow = (size_t)row * CCH + c;                       // flat
    const size_t prow = ((size_t)(row >> 10) * TP + (row & 1023) + 1) * CCH + c;

    float v[8];
    {
        bf16x8 s = *(const bf16x8*)&X[xpad ? prow : frow];
        #pragma unroll
        for (int j = 0; j < 8; ++j) v[j] = b2f(s[j]);
    }
    {
        bf16x8 s = *(const bf16x8*)&Y1b[frow];
        #pragma unroll
        for (int j = 0; j < 8; ++j) v[j] += b2f(s[j]);
    }
    if (Y2b) {
        bf16x8 s = *(const bf16x8*)&Y2b[frow];
        #pragma unroll
        for (int j = 0; j < 8; ++j) v[j] += b2f(s[j]);
    }
    float s1 = 0.f, s2 = 0.f;
    #pragma unroll
    for (int j = 0; j < 8; ++j) { s1 += v[j]; s2 += v[j] * v[j]; }
    #pragma unroll
    for (int off = 1; off < 64; off <<= 1) {
        s1 += __shfl_xor(s1, off);
        s2 += __shfl_xor(s2, off);
    }
    const float mu = s1 * (1.f / CCH);
    const float rs = rsqrtf(s2 * (1.f / CCH) - mu * mu + 1e-5f);

    const float4 g0 = *(const float4*)&g[c], g1 = *(const float4*)&g[c + 4];
    const float4 b0 = *(const float4*)&bb[c], b1 = *(const float4*)&bb[c + 4];
    float o[8];
    o[0] = (v[0] - mu) * rs * g0.x + b0.x;
    o[1] = (v[1] - mu) * rs * g0.y + b0.y;
    o[2] = (v[2] - mu) * rs * g0.z + b0.z;
    o[3] = (v[3] - mu) * rs * g0.w + b0.w;
    o[4] = (v[4] - mu) * rs * g1.x + b1.x;
    o[5] = (v[5] - mu) * rs * g1.y + b1.y;
    o[6] = (v[6] - mu) * rs * g1.z + b1.z;
    o[7] = (v[7] - mu) * rs * g1.w + b1.w;

    bf16x8 pk;
    #pragma unroll
    for (int j = 0; j < 8; ++j) pk[j] = f2b(o[j]);
    *(bf16x8*)&outB[opad ? prow : frow] = pk;
}

// ---------------------------------------------------------------------------
// Input transpose: x [B][C][T] fp32 -> curb [B*T][C] bf16
__global__ __launch_bounds__(256)
void transpose_in(const float* __restrict__ x, short* __restrict__ curb)
{
    __shared__ float tl[32][33];
    const int tx = threadIdx.x & 31, ty = threadIdx.x >> 5;
    const int t0 = blockIdx.x * 32, c0 = blockIdx.y * 32, b = blockIdx.z;
    #pragma unroll
    for (int i = 0; i < 4; ++i)
        tl[ty + i * 8][tx] = x[((size_t)b * CCH + c0 + ty + i * 8) * T_LEN + t0 + tx];
    __syncthreads();
    #pragma unroll
    for (int i = 0; i < 4; ++i) {
        const size_t orow = (size_t)b * T_LEN + t0 + ty + i * 8;
        curb[orow * CCH + c0 + tx] = f2b(tl[tx][ty + i * 8]);
    }
}

// Output transpose: curb [B*T][C] bf16 -> d_out [B][C][T] fp32
__global__ __launch_bounds__(256)
void transpose_out(const short* __restrict__ curb, float* __restrict__ out)
{
    __shared__ float tl[32][33];
    const int tx = threadIdx.x & 31, ty = threadIdx.x >> 5;
    const int t0 = blockIdx.x * 32, c0 = blockIdx.y * 32, b = blockIdx.z;
    #pragma unroll
    for (int i = 0; i < 4; ++i)
        tl[ty + i * 8][tx] = b2f(curb[((size_t)b * T_LEN + t0 + ty + i * 8) * CCH + c0 + tx]);
    __syncthreads();
    #pragma unroll
    for (int i = 0; i < 4; ++i)
        out[((size_t)b * CCH + c0 + ty + i * 8) * T_LEN + t0 + tx] = tl[tx][ty + i * 8];
}

// ---------------------------------------------------------------------------
// Fused per-layer weight conversion (unchanged).
// ---------------------------------------------------------------------------
__global__ __launch_bounds__(256)
void wconv_all(const float* __restrict__ qw, const float* __restrict__ kw,
               const float* __restrict__ vw, const float* __restrict__ ow,
               const float* __restrict__ qb, const float* __restrict__ kb,
               const float* __restrict__ vb,
               const float* __restrict__ fw1, const float* __restrict__ fw2,
               short* __restrict__ wqkv, short* __restrict__ wo,
               float* __restrict__ biasq,
               short* __restrict__ wf1o, short* __restrict__ wf2o)
{
    const int sec = blockIdx.y;
    const int idx = blockIdx.x * 256 + threadIdx.x;
    if (sec == 0) {
        const int sel = idx >> 18, r = idx & 262143;
        float v;
        if (sel == 0)      v = qw[r] * (0.125f * LOG2E);
        else if (sel == 1) v = kw[r];
        else if (sel == 2) v = vw[r];
        else               v = ow[r];
        if (sel < 3) wqkv[sel * 262144 + r] = f2b(v);
        else         wo[r] = f2b(v);
        if (idx < 1536) {
            float bv;
            if (idx < 512)       bv = qb[idx] * (0.125f * LOG2E);
            else if (idx < 1024) bv = kb[idx - 512];
            else                 bv = vb[idx - 1024];
            biasq[idx] = bv;
        }
    } else {
        const float* fw = (sec == 1) ? fw1 : fw2;
        short* out      = (sec == 1) ? wf1o : wf2o;
        const int OC = FCH * CCH;
        const float w0 = fw[3 * idx + 0];
        const float w1 = fw[3 * idx + 1];
        const float w2 = fw[3 * idx + 2];
        out[idx]          = f2b(w0);
        out[OC + idx]     = f2b(w1);
        out[2 * OC + idx] = f2b(w2);
    }
}

__global__ __launch_bounds__(256)
void zero_pads(short* __restrict__ p, int C)
{
    const int idx = blockIdx.x * 256 + threadIdx.x;
    const int r = idx / C, c = idx - r * C;
    if (r >= 64) return;
    const int batch = r >> 3, pr = r & 7;
    const size_t row = (size_t)batch * TP + (pr ? 1024 + pr : 0);
    p[row * C + c] = 0;
}

// ---------------------------------------------------------------------------
extern "C" void kernel_launch(void* const* d_in, const int* in_sizes, int n_in,
                              void* d_out, int out_size, void* d_ws, size_t ws_size,
                              hipStream_t stream)
{
    (void)in_sizes; (void)n_in; (void)out_size; (void)ws_size;

    const float* x    = (const float*)d_in[0];
    const float* qw   = (const float*)d_in[2];
    const float* qb   = (const float*)d_in[3];
    const float* kw   = (const float*)d_in[4];
    const float* kb   = (const float*)d_in[5];
    const float* vw   = (const float*)d_in[6];
    const float* vb   = (const float*)d_in[7];
    const float* ow   = (const float*)d_in[8];
    const float* obp  = (const float*)d_in[9];
    const float* erk  = (const float*)d_in[10];
    const float* erv  = (const float*)d_in[11];
    const float* ln1g = (const float*)d_in[12];
    const float* ln1b = (const float*)d_in[13];
    const float* fw1  = (const float*)d_in[14];
    const float* fb1  = (const float*)d_in[15];
    const float* fw2  = (const float*)d_in[16];
    const float* fb2  = (const float*)d_in[17];
    const float* ln2g = (const float*)d_in[18];
    const float* ln2b = (const float*)d_in[19];

    char* w = (char*)d_ws;
    size_t off = 0;
    auto alloc = [&](size_t bytes) { char* p = w + off; off += (bytes + 255) & ~(size_t)255; return p; };

    short* wqkv_b = (short*)alloc(1536 * 512 * 2);
    short* wo_b   = (short*)alloc(512 * 512 * 2);
    float* biasq  = (float*)alloc(1536 * 4);
    short* wf1_b  = (short*)alloc((size_t)3 * FCH * CCH * 2);
    short* wf2_b  = (short*)alloc((size_t)3 * CCH * FCH * 2);
    short* curb   = (short*)alloc((size_t)NB * T_LEN * CCH * 2);
    char*  uni    = alloc((size_t)NB * TP * FCH * 2);        // qkvf | at | hbb
    short* qkvf   = (short*)uni;
    short* at     = (short*)(uni + (size_t)NB * T_LEN * 1536 * 2);
    short* hbb    = (short*)uni;
    short* vty    = (short*)alloc((size_t)NB * NH * HD * T_LEN * 2);  // VT | conv2 split0
    short* yb1b   = (short*)alloc((size_t)NB * T_LEN * CCH * 2);
    short* xAb    = (short*)alloc((size_t)NB * TP * CCH * 2);

    // vty region (8.4MB): VT lives qkv..attn; conv2 split0 lives conv2..ln2
    short* VT   = vty;
    short* y2s0 = vty;

    const dim3 blk(256);

    zero_pads<<<dim3((64 * CCH + 255) / 256), blk, 0, stream>>>(xAb, CCH);
    transpose_in<<<dim3(32, 16, NB), blk, 0, stream>>>(x, curb);

    for (int i = 0; i < NL; ++i) {
        const size_t woff = (size_t)i * CCH * CCH;
        wconv_all<<<dim3(4096, 3), blk, 0, stream>>>(
            qw + woff, kw + woff, vw + woff, ow + woff,
            qb + i * CCH, kb + i * CCH, vb + i * CCH,
            fw1 + (size_t)i * FCH * CCH * 3, fw2 + (size_t)i * CCH * FCH * 3,
            wqkv_b, wo_b, biasq, wf1_b, wf2_b);

        // fused q|k|v projection with V written transposed directly to VT
        mfma_gemm<1, false, 0, true><<<dim3(64, 12, 1), blk, 0, stream>>>(
            curb, wqkv_b, biasq, qkvf, nullptr, VT, CCH, 1536, 1);

        attn_mfma<<<dim3(512), dim3(512), 0, stream>>>(
            qkvf, VT, erk + (size_t)i * 9 * HD, erv + (size_t)i * 9 * HD, at);

        // output projection -> bf16 (+bias)
        mfma_gemm<1, false, 0, false><<<dim3(64, 4, 1), blk, 0, stream>>>(
            at, wo_b, obp + i * CCH, yb1b, nullptr, nullptr, CCH, CCH, 1);

        // LN1: X = curb (flat), out = xAb (padded)
        ln_kernel<<<dim3(2048), blk, 0, stream>>>(
            curb, yb1b, nullptr, ln1g + i * CCH, ln1b + i * CCH, xAb, 0, 1);

        // FFN conv1 (relu) -> padded bf16 hidden: 256^2 counted-vmcnt pipeline
        conv1_256<<<dim3(4, 8, NB), dim3(512), 0, stream>>>(
            xAb, wf1_b, fb1 + i * FCH, hbb);

        // FFN conv2, split-K=2: split0 -> bf16 y2s0 (+bias), split1 -> bf16 yb1b
        mfma_gemm<3, false, 2, false><<<dim3(8, 4, NB * 2), blk, 0, stream>>>(
            hbb, wf2_b, fb2 + i * CCH, y2s0, yb1b, nullptr, FCH, CCH, 2);

        // LN2: X = xAb (padded), out = curb (flat)
        ln_kernel<<<dim3(2048), blk, 0, stream>>>(
            xAb, y2s0, yb1b, ln2g + i * CCH, ln2b + i * CCH, curb, 1, 0);
    }

    transpose_out<<<dim3(32, 16, NB), blk, 0, stream>>>(curb, (float*)d_out);
}

// Round 18
// 1412.572 us; speedup vs baseline: 1.1647x; 1.1647x over previous
//
#include <hip/hip_runtime.h>
#include <hip/hip_bf16.h>
#include <math.h>

#define T_LEN 1024
#define NB    8
#define CCH   512
#define FCH   2048
#define NH    8
#define HD    64
#define NL    6
#define TP    1032   // padded time rows per batch: [1 pre][1024][7 post]
#define LOG2E 1.44269504f

typedef short bf16x8 __attribute__((ext_vector_type(8)));
typedef float f32x4  __attribute__((ext_vector_type(4)));

typedef __attribute__((address_space(1))) const void gvoid_t;
typedef __attribute__((address_space(3))) void lvoid_t;

static __device__ __forceinline__ float b2f(short s) {
    union { unsigned u; float f; } cv; cv.u = ((unsigned)(unsigned short)s) << 16; return cv.f;
}
static __device__ __forceinline__ short f2b(float f) {
    union { __hip_bfloat16 h; short s; } cv; cv.h = __float2bfloat16(f); return cv.s;
}
// raw v_exp_f32: D = 2^S0
static __device__ __forceinline__ float exp2_hw(float x) {
    float r; asm("v_exp_f32 %0, %1" : "=v"(r) : "v"(x)); return r;
}

// ---------------------------------------------------------------------------
// conv1 256x256 counted-vmcnt pipelined GEMM (KS=3, relu, padded bf16 out).
// Proven R16: 8 waves, BK=64, LDS 128KB dbuf, vmcnt(4), no sched pins.
// ---------------------------------------------------------------------------
__global__ __launch_bounds__(512)
void conv1_256(const short* __restrict__ Xb, const short* __restrict__ Wb,
               const float* __restrict__ Bias, short* __restrict__ outB)
{
    __shared__ short abuf[2][256 * 64];
    __shared__ short bbuf[2][256 * 64];

    const int tid  = threadIdx.x;
    const int wave = tid >> 6, lane = tid & 63;
    const int l15  = lane & 15, l16 = lane >> 4;
    const int wm   = wave >> 2, wn = wave & 3;
    const int srow = lane >> 3;
    const int xsw  = ((lane & 7) ^ (srow & 7)) << 3;

    const int t0 = blockIdx.x * 256;
    const int o0 = blockIdx.y * 256;
    const int b  = blockIdx.z;

    constexpr int NK = 24;               // 3 taps x 8 chunks of 64
    const size_t arow0 = (size_t)b * TP + t0;

    auto stageA = [&](int kcg, short* dst) {
        const int tap = kcg >> 3;
        const int c0  = (kcg & 7) << 6;
        const short* base = Xb + (arow0 + tap) * CCH + c0 + xsw;
        #pragma unroll
        for (int i = 0; i < 4; ++i) {
            const int j = wave + 8 * i;
            __builtin_amdgcn_global_load_lds((gvoid_t*)(base + (size_t)(j * 8 + srow) * CCH),
                                             (lvoid_t*)(dst + j * 512), 16, 0, 0);
        }
    };
    auto stageB = [&](int kcg, short* dst) {
        const int tap = kcg >> 3;
        const int c0  = (kcg & 7) << 6;
        const short* base = Wb + ((size_t)tap * FCH + o0) * CCH + c0 + xsw;
        #pragma unroll
        for (int i = 0; i < 4; ++i) {
            const int j = wave + 8 * i;
            __builtin_amdgcn_global_load_lds((gvoid_t*)(base + (size_t)(j * 8 + srow) * CCH),
                                             (lvoid_t*)(dst + j * 512), 16, 0, 0);
        }
    };

    f32x4 acc[8][4];
    #pragma unroll
    for (int i = 0; i < 8; ++i)
        #pragma unroll
        for (int j = 0; j < 4; ++j) acc[i][j] = (f32x4){0.f, 0.f, 0.f, 0.f};

    stageA(0, abuf[0]);
    stageB(0, bbuf[0]);

    for (int kc = 0; kc < NK; ++kc) {
        const int cur = kc & 1, nxt = cur ^ 1;
        const int kn  = (kc + 1 < NK) ? (kc + 1) : kc;

        __builtin_amdgcn_s_barrier();
        stageA(kn, abuf[nxt]);
        asm volatile("s_waitcnt vmcnt(4)" ::: "memory");
        __builtin_amdgcn_s_barrier();

        #pragma unroll
        for (int ks = 0; ks < 2; ++ks) {
            if (ks == 1) stageB(kn, bbuf[nxt]);
            bf16x8 af[8], bfr[4];
            #pragma unroll
            for (int fm = 0; fm < 8; ++fm) {
                const int ra = wm * 128 + fm * 16 + l15;
                af[fm] = *(const bf16x8*)&abuf[cur][ra * 64 + (((ks * 4 + l16) ^ (ra & 7)) << 3)];
            }
            #pragma unroll
            for (int fn = 0; fn < 4; ++fn) {
                const int rb = wn * 64 + fn * 16 + l15;
                bfr[fn] = *(const bf16x8*)&bbuf[cur][rb * 64 + (((ks * 4 + l16) ^ (rb & 7)) << 3)];
            }
            __builtin_amdgcn_s_setprio(1);
            #pragma unroll
            for (int fm = 0; fm < 8; ++fm)
                #pragma unroll
                for (int fn = 0; fn < 4; ++fn)
                    acc[fm][fn] = __builtin_amdgcn_mfma_f32_16x16x32_bf16(
                        af[fm], bfr[fn], acc[fm][fn], 0, 0, 0);
            __builtin_amdgcn_s_setprio(0);
        }
    }

    float bias_v[4];
    #pragma unroll
    for (int fn = 0; fn < 4; ++fn)
        bias_v[fn] = Bias[o0 + wn * 64 + fn * 16 + l15];

    #pragma unroll
    for (int fm = 0; fm < 8; ++fm) {
        #pragma unroll
        for (int r = 0; r < 4; ++r) {
            const int t_loc = wm * 128 + fm * 16 + l16 * 4 + r;
            const size_t orow = (size_t)b * TP + t0 + t_loc + 1;
            #pragma unroll
            for (int fn = 0; fn < 4; ++fn) {
                const int o = o0 + wn * 64 + fn * 16 + l15;
                outB[orow * FCH + o] = f2b(fmaxf(acc[fm][fn][r] + bias_v[fn], 0.f));
            }
        }
    }

    if (t0 == 0)
        for (int cc = tid; cc < 256; cc += 512)
            outB[((size_t)b * TP) * FCH + o0 + cc] = 0;
    if (t0 == T_LEN - 256)
        for (int idx = tid; idx < 7 * 256; idx += 512) {
            const int rr = idx >> 8, cc = idx & 255;
            outB[((size_t)b * TP + 1025 + rr) * FCH + o0 + cc] = 0;
        }
}

// ---------------------------------------------------------------------------
// 128x128 MFMA GEMM / conv1d (proven R1-R16 structure, 32KB LDS, implicit
// wave-overlap via occupancy).  All outputs bf16.
// OMODE: 0 bf16 flat [rows][O]; 2 split-K=2.
// VTOUT: blocks with o0>=1024 write a transposed copy to VTout via LDS
//        re-stage and skip the flat store.
// ---------------------------------------------------------------------------
template<int KSZ, bool RELU, int OMODE, bool VTOUT>
__global__ __launch_bounds__(256)
void mfma_gemm(const short* __restrict__ Xb, const short* __restrict__ Wb,
               const float* __restrict__ Bias,
               short* __restrict__ outB1, short* __restrict__ outB2,
               short* __restrict__ VTout,
               int Cin, int O, int ksplit)
{
    constexpr int XR = (KSZ == 3) ? 136 : 128;
    __shared__ short shmem[(XR + 128) * 64];   // xl | wl; reused as 128x128 tb
    short* xl = shmem;
    short* wl = shmem + XR * 64;

    const int tid  = threadIdx.x;
    const int wave = tid >> 6, lane = tid & 63;
    const int l15  = lane & 15, l16 = lane >> 4;
    const int wm   = wave >> 1, wn = wave & 1;

    const int t0 = blockIdx.x * 128;
    const int o0 = blockIdx.y * 128;
    const int zz = blockIdx.z;
    const int b     = zz / ksplit;
    const int split = zz - b * ksplit;
    const int kcin  = Cin / ksplit;
    const int cbeg  = split * kcin;

    const size_t xrowbase = (KSZ == 3) ? ((size_t)b * TP + t0) : (size_t)t0;

    const int srow = lane >> 3;
    const int xsw  = ((lane & 7) ^ (srow & 7)) << 3;

    f32x4 acc[4][4];
    #pragma unroll
    for (int i = 0; i < 4; ++i)
        #pragma unroll
        for (int j = 0; j < 4; ++j) acc[i][j] = (f32x4){0.f, 0.f, 0.f, 0.f};

    for (int cb = 0; cb < kcin; cb += 64) {
        const int c0 = cbeg + cb;
        __syncthreads();
        for (int j = wave; j < XR / 8; j += 4) {
            const short* src = Xb + (xrowbase + (size_t)(j * 8 + srow)) * Cin + c0 + xsw;
            __builtin_amdgcn_global_load_lds((gvoid_t*)src, (lvoid_t*)&xl[j * 512], 16, 0, 0);
        }
        #pragma unroll
        for (int kk = 0; kk < KSZ; ++kk) {
            if (kk > 0) __syncthreads();
            for (int j = wave; j < 16; j += 4) {
                const short* src = Wb + ((size_t)kk * O + o0 + j * 8 + srow) * Cin + c0 + xsw;
                __builtin_amdgcn_global_load_lds((gvoid_t*)src, (lvoid_t*)&wl[j * 512], 16, 0, 0);
            }
            __syncthreads();
            #pragma unroll
            for (int ks = 0; ks < 2; ++ks) {
                bf16x8 af[4], bfr[4];
                #pragma unroll
                for (int f = 0; f < 4; ++f) {
                    const int ra = wm * 64 + f * 16 + l15 + (KSZ == 3 ? kk : 0);
                    af[f] = *(const bf16x8*)&xl[ra * 64 + (((ks * 4 + l16) ^ (ra & 7)) << 3)];
                    const int rb = wn * 64 + f * 16 + l15;
                    bfr[f] = *(const bf16x8*)&wl[rb * 64 + (((ks * 4 + l16) ^ (rb & 7)) << 3)];
                }
                #pragma unroll
                for (int fm = 0; fm < 4; ++fm)
                    #pragma unroll
                    for (int fn = 0; fn < 4; ++fn)
                        acc[fm][fn] = __builtin_amdgcn_mfma_f32_16x16x32_bf16(
                            af[fm], bfr[fn], acc[fm][fn], 0, 0, 0);
            }
        }
    }

    float bias_v[4];
    #pragma unroll
    for (int fn = 0; fn < 4; ++fn)
        bias_v[fn] = (OMODE != 2 || split == 0) ? Bias[o0 + wn * 64 + fn * 16 + l15] : 0.f;

    const bool vtblk = VTOUT && (o0 >= 1024);

    if (vtblk) {
        // V third of qkv: transpose via LDS, skip flat store.
        __syncthreads();   // all waves done with xl/wl
        short* tb = shmem;  // 128(o_local) x 128(t_loc), chunk-XOR swizzled
        #pragma unroll
        for (int fm = 0; fm < 4; ++fm)
            #pragma unroll
            for (int r = 0; r < 4; ++r) {
                const int t_loc = wm * 64 + fm * 16 + l16 * 4 + r;
                #pragma unroll
                for (int fn = 0; fn < 4; ++fn) {
                    const int ol = wn * 64 + fn * 16 + l15;
                    tb[ol * 128 + (((t_loc >> 3) ^ (ol & 7)) << 3) + (t_loc & 7)]
                        = f2b(acc[fm][fn][r] + bias_v[fn]);
                }
            }
        __syncthreads();
        const int bq  = t0 >> 10, tin = t0 & 1023;
        const int vcb = o0 - 1024;
        #pragma unroll
        for (int p = 0; p < 8; ++p) {
            const int drow  = (tid >> 4) + p * 16;
            const int chunk = tid & 15;   // 16 chunks of 8 elems per 128-row
            bf16x8 v = *(const bf16x8*)&tb[drow * 128 + ((chunk ^ (drow & 7)) << 3)];
            const int vc = vcb + drow;
            *(bf16x8*)&VTout[((size_t)(bq * NH + (vc >> 6)) * HD + (vc & 63)) * T_LEN
                             + tin + chunk * 8] = v;
        }
    } else {
        #pragma unroll
        for (int fm = 0; fm < 4; ++fm) {
            #pragma unroll
            for (int r = 0; r < 4; ++r) {
                const int t_loc = wm * 64 + fm * 16 + l16 * 4 + r;
                const size_t orow = (KSZ == 3) ? ((size_t)b * T_LEN + t0 + t_loc)
                                               : (size_t)(t0 + t_loc);
                #pragma unroll
                for (int fn = 0; fn < 4; ++fn) {
                    const int o = o0 + wn * 64 + fn * 16 + l15;
                    float v = acc[fm][fn][r] + bias_v[fn];
                    if (RELU) v = fmaxf(v, 0.f);
                    const size_t idx = orow * (size_t)O + o;
                    if (OMODE == 2) {
                        if (split == 0) outB1[idx] = f2b(v);
                        else            outB2[idx] = f2b(v);
                    } else {
                        outB1[idx] = f2b(v);
                    }
                }
            }
        }
    }
}

// ---------------------------------------------------------------------------
// MFMA flash attention — proven 86.5 us form (unchanged).
// ---------------------------------------------------------------------------
__global__ __launch_bounds__(512)
void attn_mfma(const short* __restrict__ QKV, const short* __restrict__ VT,
               const float* __restrict__ erk, const float* __restrict__ erv,
               short* __restrict__ Yat)
{
    const int n = blockIdx.x;
    const int c = n & 7, g = n >> 3;
    const int bh = c * 8 + (g & 7);
    const int qt = g >> 3;
    const int b = bh >> 3, h = bh & 7;
    const int tq0 = qt * 128;
    const int hq = h * HD;
    const size_t bt0 = (size_t)b * T_LEN;

    __shared__ short ql[128 * 64];   // prologue: Q; main loop: pl buffer (odd tiles)
    __shared__ short pl0[128 * 64];  // pl buffer (even tiles)
    __shared__ short kl[2][64 * 64];
    __shared__ short vl[2][64 * 64];
    __shared__ float qerkl[128][12];
    __shared__ float ervl[9][64];

    const int tid  = threadIdx.x;
    const int wave = tid >> 6, lane = tid & 63;
    const int l15  = lane & 15, l16 = lane >> 4;
    const int srow = lane >> 3;
    const int xsw  = ((lane & 7) ^ (srow & 7)) << 3;

    const short* vbase = VT + (size_t)bh * HD * T_LEN;

    for (int j = wave; j < 16; j += 8) {
        const short* src = QKV + (bt0 + tq0 + j * 8 + srow) * 1536 + hq + xsw;
        __builtin_amdgcn_global_load_lds((gvoid_t*)src, (lvoid_t*)&ql[j * 512], 16, 0, 0);
    }
    {
        const short* ksrc = QKV + (bt0 + wave * 8 + srow) * 1536 + 512 + hq + xsw;
        __builtin_amdgcn_global_load_lds((gvoid_t*)ksrc, (lvoid_t*)&kl[0][wave * 512], 16, 0, 0);
        const short* vsrc = vbase + (size_t)(wave * 8 + srow) * T_LEN + xsw;
        __builtin_amdgcn_global_load_lds((gvoid_t*)vsrc, (lvoid_t*)&vl[0][wave * 512], 16, 0, 0);
    }
    for (int i = tid; i < 9 * 64; i += 512) ervl[i >> 6][i & 63] = erv[i];
    __syncthreads();   // Q/K0/V0 landed; ervl visible

    // Q A-fragments -> registers
    bf16x8 af[2];
    #pragma unroll
    for (int ks = 0; ks < 2; ++ks) {
        const int r0 = wave * 16 + l15;
        af[ks] = *(const bf16x8*)&ql[r0 * 64 + (((ks * 4 + l16) ^ (r0 & 7)) << 3)];
    }

    // qerk[r][o] = q[r].erk[o]  (q carries log2e)
    for (int idx = tid; idx < 128 * 9; idx += 512) {
        const int r = idx / 9, o = idx - r * 9;
        float s = 0.f;
        for (int d = 0; d < 64; ++d) {
            float qv = b2f(ql[r * 64 + (((d >> 3) ^ (r & 7)) << 3) + (d & 7)]);
            s += qv * erk[o * 64 + d];
        }
        qerkl[r][o] = s;
    }

    float lsum[4] = {0.f, 0.f, 0.f, 0.f};
    f32x4 acco[4];
    #pragma unroll
    for (int fn = 0; fn < 4; ++fn) acco[fn] = (f32x4){0.f, 0.f, 0.f, 0.f};
    bf16x8 vf[2][4];   // V fragments of the previous tile

    const int ra = wave * 16 + l15;

    for (int it = 0; it < 16; ++it) {
        const int cur = it & 1;
        const int s0  = it * 64;
        __syncthreads();   // stage(it) landed; prev-iter ds_reads drained

        if (it < 15) {     // prefetch tile it+1
            const short* ksrc = QKV + (bt0 + s0 + 64 + wave * 8 + srow) * 1536 + 512 + hq + xsw;
            __builtin_amdgcn_global_load_lds((gvoid_t*)ksrc, (lvoid_t*)&kl[cur ^ 1][wave * 512], 16, 0, 0);
            const short* vsrc = vbase + (size_t)(wave * 8 + srow) * T_LEN + s0 + 64 + xsw;
            __builtin_amdgcn_global_load_lds((gvoid_t*)vsrc, (lvoid_t*)&vl[cur ^ 1][wave * 512], 16, 0, 0);
        }

        // QK^T(it)
        f32x4 sc[4];
        #pragma unroll
        for (int fn = 0; fn < 4; ++fn) sc[fn] = (f32x4){0.f, 0.f, 0.f, 0.f};
        __builtin_amdgcn_s_setprio(1);
        #pragma unroll
        for (int ks = 0; ks < 2; ++ks)
            #pragma unroll
            for (int fn = 0; fn < 4; ++fn) {
                const int rb = fn * 16 + l15;
                bf16x8 bf = *(const bf16x8*)&kl[cur][rb * 64 + (((ks * 4 + l16) ^ (rb & 7)) << 3)];
                sc[fn] = __builtin_amdgcn_mfma_f32_16x16x32_bf16(af[ks], bf, sc[fn], 0, 0, 0);
            }
        __builtin_amdgcn_s_setprio(0);

        // PV(it-1) + rel-v(it-1): prev pl buffer + vf registers
        if (it > 0) {
            short* plp = cur ? pl0 : ql;
            __builtin_amdgcn_s_setprio(1);
            #pragma unroll
            for (int ks = 0; ks < 2; ++ks) {
                bf16x8 paf = *(const bf16x8*)&plp[ra * 64 + (((ks * 4 + l16) ^ (ra & 7)) << 3)];
                #pragma unroll
                for (int fn = 0; fn < 4; ++fn)
                    acco[fn] = __builtin_amdgcn_mfma_f32_16x16x32_bf16(paf, vf[ks][fn], acco[fn], 0, 0, 0);
            }
            __builtin_amdgcn_s_setprio(0);
            const int s0p = s0 - 64;
            if ((s0p >= tq0 - 64) && (s0p <= tq0 + 128)) {
                #pragma unroll
                for (int r = 0; r < 4; ++r) {
                    const int q_loc = wave * 16 + l16 * 4 + r;
                    const int qg = tq0 + q_loc;
                    #pragma unroll
                    for (int o = 0; o < 9; ++o) {
                        const int jj = qg + o - 4 - s0p;
                        if (jj >= 0 && jj < 64) {
                            const float p = b2f(plp[q_loc * 64
                                + (((jj >> 3) ^ (q_loc & 7)) << 3) + (jj & 7)]);
                            #pragma unroll
                            for (int fn = 0; fn < 4; ++fn)
                                acco[fn][r] += p * ervl[o][fn * 16 + l15];
                        }
                    }
                }
            }
        }

        // hoist V(it) fragments -> registers (consumed next iter / epilogue)
        #pragma unroll
        for (int ks = 0; ks < 2; ++ks)
            #pragma unroll
            for (int fn = 0; fn < 4; ++fn) {
                const int rb = fn * 16 + l15;
                vf[ks][fn] = *(const bf16x8*)&vl[cur][rb * 64 + (((ks * 4 + l16) ^ (rb & 7)) << 3)];
            }

        // rel-k band + exp2 softmax
        if ((s0 >= tq0 - 64) && (s0 <= tq0 + 128)) {
            #pragma unroll
            for (int fn = 0; fn < 4; ++fn)
                #pragma unroll
                for (int r = 0; r < 4; ++r) {
                    const int q_loc = wave * 16 + l16 * 4 + r;
                    const int off = (s0 + fn * 16 + l15) - (tq0 + q_loc);
                    if (off >= -4 && off <= 4)
                        sc[fn][r] += qerkl[q_loc][off + 4];
                }
        }
        #pragma unroll
        for (int fn = 0; fn < 4; ++fn)
            #pragma unroll
            for (int r = 0; r < 4; ++r) {
                const float p = exp2_hw(sc[fn][r]);
                sc[fn][r] = p;
                lsum[r] += p;
            }

        // write P(it) into this tile's pl buffer (wave-private rows)
        {
            short* plw = cur ? ql : pl0;
            #pragma unroll
            for (int fn = 0; fn < 4; ++fn)
                #pragma unroll
                for (int r = 0; r < 4; ++r) {
                    const int q_loc = wave * 16 + l16 * 4 + r;
                    const int s_loc = fn * 16 + l15;
                    plw[q_loc * 64 + (((s_loc >> 3) ^ (q_loc & 7)) << 3) + (s_loc & 7)]
                        = f2b(sc[fn][r]);
                }
        }
    }

    // epilogue: PV(15) + rel-v(15)
    __syncthreads();
    {
        short* plp = ql;
        #pragma unroll
        for (int ks = 0; ks < 2; ++ks) {
            bf16x8 paf = *(const bf16x8*)&plp[ra * 64 + (((ks * 4 + l16) ^ (ra & 7)) << 3)];
            #pragma unroll
            for (int fn = 0; fn < 4; ++fn)
                acco[fn] = __builtin_amdgcn_mfma_f32_16x16x32_bf16(paf, vf[ks][fn], acco[fn], 0, 0, 0);
        }
        const int s0p = 960;
        if ((s0p >= tq0 - 64) && (s0p <= tq0 + 128)) {
            #pragma unroll
            for (int r = 0; r < 4; ++r) {
                const int q_loc = wave * 16 + l16 * 4 + r;
                const int qg = tq0 + q_loc;
                #pragma unroll
                for (int o = 0; o < 9; ++o) {
                    const int jj = qg + o - 4 - s0p;
                    if (jj >= 0 && jj < 64) {
                        const float p = b2f(plp[q_loc * 64
                            + (((jj >> 3) ^ (q_loc & 7)) << 3) + (jj & 7)]);
                        #pragma unroll
                        for (int fn = 0; fn < 4; ++fn)
                            acco[fn][r] += p * ervl[o][fn * 16 + l15];
                    }
                }
            }
        }
    }

    #pragma unroll
    for (int r = 0; r < 4; ++r) {
        float l = lsum[r];
        l += __shfl_xor(l, 1);
        l += __shfl_xor(l, 2);
        l += __shfl_xor(l, 4);
        l += __shfl_xor(l, 8);
        const float inv = 1.f / l;
        const int q_loc = wave * 16 + l16 * 4 + r;
        const size_t row = (bt0 + tq0 + q_loc) * CCH + hq;
        #pragma unroll
        for (int fn = 0; fn < 4; ++fn)
            Yat[row + fn * 16 + l15] = f2b(acco[fn][r] * inv);
    }
}

// ---------------------------------------------------------------------------
// Residual + LayerNorm, full-bf16 stream: out = LN(X + Y1b [+ Y2b]) * g + b.
// X may live in padded rows (xpad); output may be written padded (opad).
// ---------------------------------------------------------------------------
__global__ __launch_bounds__(256)
void ln_kernel(const short* __restrict__ X, const short* __restrict__ Y1b,
               const short* __restrict__ Y2b, const float* __restrict__ g,
               const float* __restrict__ bb, short* __restrict__ outB,
               int xpad, int opad)
{
    const int wave = threadIdx.x >> 6, lane = threadIdx.x & 63;
    const int row  = blockIdx.x * 4 + wave;
    const int c = lane * 8;
    const size_t frow = (size_t)row * CCH + c;                       // flat
    const size_t prow = ((size_t)(row >> 10) * TP + (row & 1023) + 1) * CCH + c;

    float v[8];
    {
        bf16x8 s = *(const bf16x8*)&X[xpad ? prow : frow];
        #pragma unroll
        for (int j = 0; j < 8; ++j) v[j] = b2f(s[j]);
    }
    {
        bf16x8 s = *(const bf16x8*)&Y1b[frow];
        #pragma unroll
        for (int j = 0; j < 8; ++j) v[j] += b2f(s[j]);
    }
    if (Y2b) {
        bf16x8 s = *(const bf16x8*)&Y2b[frow];
        #pragma unroll
        for (int j = 0; j < 8; ++j) v[j] += b2f(s[j]);
    }
    float s1 = 0.f, s2 = 0.f;
    #pragma unroll
    for (int j = 0; j < 8; ++j) { s1 += v[j]; s2 += v[j] * v[j]; }
    #pragma unroll
    for (int off = 1; off < 64; off <<= 1) {
        s1 += __shfl_xor(s1, off);
        s2 += __shfl_xor(s2, off);
    }
    const float mu = s1 * (1.f / CCH);
    const float rs = rsqrtf(s2 * (1.f / CCH) - mu * mu + 1e-5f);

    const float4 g0 = *(const float4*)&g[c], g1 = *(const float4*)&g[c + 4];
    const float4 b0 = *(const float4*)&bb[c], b1 = *(const float4*)&bb[c + 4];
    float o[8];
    o[0] = (v[0] - mu) * rs * g0.x + b0.x;
    o[1] = (v[1] - mu) * rs * g0.y + b0.y;
    o[2] = (v[2] - mu) * rs * g0.z + b0.z;
    o[3] = (v[3] - mu) * rs * g0.w + b0.w;
    o[4] = (v[4] - mu) * rs * g1.x + b1.x;
    o[5] = (v[5] - mu) * rs * g1.y + b1.y;
    o[6] = (v[6] - mu) * rs * g1.z + b1.z;
    o[7] = (v[7] - mu) * rs * g1.w + b1.w;

    bf16x8 pk;
    #pragma unroll
    for (int j = 0; j < 8; ++j) pk[j] = f2b(o[j]);
    *(bf16x8*)&outB[opad ? prow : frow] = pk;
}

// ---------------------------------------------------------------------------
// Input transpose: x [B][C][T] fp32 -> curb [B*T][C] bf16
__global__ __launch_bounds__(256)
void transpose_in(const float* __restrict__ x, short* __restrict__ curb)
{
    __shared__ float tl[32][33];
    const int tx = threadIdx.x & 31, ty = threadIdx.x >> 5;
    const int t0 = blockIdx.x * 32, c0 = blockIdx.y * 32, b = blockIdx.z;
    #pragma unroll
    for (int i = 0; i < 4; ++i)
        tl[ty + i * 8][tx] = x[((size_t)b * CCH + c0 + ty + i * 8) * T_LEN + t0 + tx];
    __syncthreads();
    #pragma unroll
    for (int i = 0; i < 4; ++i) {
        const size_t orow = (size_t)b * T_LEN + t0 + ty + i * 8;
        curb[orow * CCH + c0 + tx] = f2b(tl[tx][ty + i * 8]);
    }
}

// Output transpose: curb [B*T][C] bf16 -> d_out [B][C][T] fp32
__global__ __launch_bounds__(256)
void transpose_out(const short* __restrict__ curb, float* __restrict__ out)
{
    __shared__ float tl[32][33];
    const int tx = threadIdx.x & 31, ty = threadIdx.x >> 5;
    const int t0 = blockIdx.x * 32, c0 = blockIdx.y * 32, b = blockIdx.z;
    #pragma unroll
    for (int i = 0; i < 4; ++i)
        tl[ty + i * 8][tx] = b2f(curb[((size_t)b * T_LEN + t0 + ty + i * 8) * CCH + c0 + tx]);
    __syncthreads();
    #pragma unroll
    for (int i = 0; i < 4; ++i)
        out[((size_t)b * CCH + c0 + ty + i * 8) * T_LEN + t0 + tx] = tl[tx][ty + i * 8];
}

// ---------------------------------------------------------------------------
// Fused per-layer weight conversion.  blockIdx.y: 0 = qkv/wo/bias, 1 = fw1,
// 2 = fw2.  q weights & bias carry 0.125*log2e (exp2 softmax upstream).
// ---------------------------------------------------------------------------
__global__ __launch_bounds__(256)
void wconv_all(const float* __restrict__ qw, const float* __restrict__ kw,
               const float* __restrict__ vw, const float* __restrict__ ow,
               const float* __restrict__ qb, const float* __restrict__ kb,
               const float* __restrict__ vb,
               const float* __restrict__ fw1, const float* __restrict__ fw2,
               short* __restrict__ wqkv, short* __restrict__ wo,
               float* __restrict__ biasq,
               short* __restrict__ wf1o, short* __restrict__ wf2o)
{
    const int sec = blockIdx.y;
    const int idx = blockIdx.x * 256 + threadIdx.x;
    if (sec == 0) {
        const int sel = idx >> 18, r = idx & 262143;
        float v;
        if (sel == 0)      v = qw[r] * (0.125f * LOG2E);
        else if (sel == 1) v = kw[r];
        else if (sel == 2) v = vw[r];
        else               v = ow[r];
        if (sel < 3) wqkv[sel * 262144 + r] = f2b(v);
        else         wo[r] = f2b(v);
        if (idx < 1536) {
            float bv;
            if (idx < 512)       bv = qb[idx] * (0.125f * LOG2E);
            else if (idx < 1024) bv = kb[idx - 512];
            else                 bv = vb[idx - 1024];
            biasq[idx] = bv;
        }
    } else {
        const float* fw = (sec == 1) ? fw1 : fw2;
        short* out      = (sec == 1) ? wf1o : wf2o;
        const int OC = FCH * CCH;
        const float w0 = fw[3 * idx + 0];
        const float w1 = fw[3 * idx + 1];
        const float w2 = fw[3 * idx + 2];
        out[idx]          = f2b(w0);
        out[OC + idx]     = f2b(w1);
        out[2 * OC + idx] = f2b(w2);
    }
}

__global__ __launch_bounds__(256)
void zero_pads(short* __restrict__ p, int C)
{
    const int idx = blockIdx.x * 256 + threadIdx.x;
    const int r = idx / C, c = idx - r * C;
    if (r >= 64) return;
    const int batch = r >> 3, pr = r & 7;
    const size_t row = (size_t)batch * TP + (pr ? 1024 + pr : 0);
    p[row * C + c] = 0;
}

// ---------------------------------------------------------------------------
extern "C" void kernel_launch(void* const* d_in, const int* in_sizes, int n_in,
                              void* d_out, int out_size, void* d_ws, size_t ws_size,
                              hipStream_t stream)
{
    (void)in_sizes; (void)n_in; (void)out_size; (void)ws_size;

    const float* x    = (const float*)d_in[0];
    const float* qw   = (const float*)d_in[2];
    const float* qb   = (const float*)d_in[3];
    const float* kw   = (const float*)d_in[4];
    const float* kb   = (const float*)d_in[5];
    const float* vw   = (const float*)d_in[6];
    const float* vb   = (const float*)d_in[7];
    const float* ow   = (const float*)d_in[8];
    const float* obp  = (const float*)d_in[9];
    const float* erk  = (const float*)d_in[10];
    const float* erv  = (const float*)d_in[11];
    const float* ln1g = (const float*)d_in[12];
    const float* ln1b = (const float*)d_in[13];
    const float* fw1  = (const float*)d_in[14];
    const float* fb1  = (const float*)d_in[15];
    const float* fw2  = (const float*)d_in[16];
    const float* fb2  = (const float*)d_in[17];
    const float* ln2g = (const float*)d_in[18];
    const float* ln2b = (const float*)d_in[19];

    char* w = (char*)d_ws;
    size_t off = 0;
    auto alloc = [&](size_t bytes) { char* p = w + off; off += (bytes + 255) & ~(size_t)255; return p; };

    short* wqkv_b = (short*)alloc(1536 * 512 * 2);
    short* wo_b   = (short*)alloc(512 * 512 * 2);
    float* biasq  = (float*)alloc(1536 * 4);
    short* wf1_b  = (short*)alloc((size_t)3 * FCH * CCH * 2);
    short* wf2_b  = (short*)alloc((size_t)3 * CCH * FCH * 2);
    short* curb   = (short*)alloc((size_t)NB * T_LEN * CCH * 2);
    char*  uni    = alloc((size_t)NB * TP * FCH * 2);        // qkvf | at | hbb
    short* qkvf   = (short*)uni;
    short* at     = (short*)(uni + (size_t)NB * T_LEN * 1536 * 2);
    short* hbb    = (short*)uni;
    short* vty    = (short*)alloc((size_t)NB * NH * HD * T_LEN * 2);  // VT | conv2 split0
    short* yb1b   = (short*)alloc((size_t)NB * T_LEN * CCH * 2);
    short* xAb    = (short*)alloc((size_t)NB * TP * CCH * 2);

    // vty region (8.4MB): VT lives qkv..attn; conv2 split0 lives conv2..ln2
    short* VT   = vty;
    short* y2s0 = vty;

    const dim3 blk(256);

    zero_pads<<<dim3((64 * CCH + 255) / 256), blk, 0, stream>>>(xAb, CCH);
    transpose_in<<<dim3(32, 16, NB), blk, 0, stream>>>(x, curb);

    for (int i = 0; i < NL; ++i) {
        const size_t woff = (size_t)i * CCH * CCH;
        wconv_all<<<dim3(4096, 3), blk, 0, stream>>>(
            qw + woff, kw + woff, vw + woff, ow + woff,
            qb + i * CCH, kb + i * CCH, vb + i * CCH,
            fw1 + (size_t)i * FCH * CCH * 3, fw2 + (size_t)i * CCH * FCH * 3,
            wqkv_b, wo_b, biasq, wf1_b, wf2_b);

        // fused q|k|v projection with V written transposed directly to VT
        mfma_gemm<1, false, 0, true><<<dim3(64, 12, 1), blk, 0, stream>>>(
            curb, wqkv_b, biasq, qkvf, nullptr, VT, CCH, 1536, 1);

        attn_mfma<<<dim3(512), dim3(512), 0, stream>>>(
            qkvf, VT, erk + (size_t)i * 9 * HD, erv + (size_t)i * 9 * HD, at);

        // output projection -> bf16 (+bias)
        mfma_gemm<1, false, 0, false><<<dim3(64, 4, 1), blk, 0, stream>>>(
            at, wo_b, obp + i * CCH, yb1b, nullptr, nullptr, CCH, CCH, 1);

        // LN1: X = curb (flat), out = xAb (padded)
        ln_kernel<<<dim3(2048), blk, 0, stream>>>(
            curb, yb1b, nullptr, ln1g + i * CCH, ln1b + i * CCH, xAb, 0, 1);

        // FFN conv1 (relu) -> padded bf16 hidden: 256^2 counted-vmcnt pipeline
        conv1_256<<<dim3(4, 8, NB), dim3(512), 0, stream>>>(
            xAb, wf1_b, fb1 + i * FCH, hbb);

        // FFN conv2, split-K=2: split0 -> bf16 y2s0 (+bias), split1 -> bf16 yb1b
        mfma_gemm<3, false, 2, false><<<dim3(8, 4, NB * 2), blk, 0, stream>>>(
            hbb, wf2_b, fb2 + i * CCH, y2s0, yb1b, nullptr, FCH, CCH, 2);

        // LN2: X = xAb (padded), out = curb (flat)
        ln_kernel<<<dim3(2048), blk, 0, stream>>>(
            xAb, y2s0, yb1b, ln2g + i * CCH, ln2b + i * CCH, curb, 1, 0);
    }

    transpose_out<<<dim3(32, 16, NB), blk, 0, stream>>>(curb, (float*)d_out);
}